// Round 8
// baseline (55.067 us; speedup 1.0000x reference)
//
#include <hip/hip_runtime.h>
#include <stdint.h>

// QuantConv1D (binary, K=3, Cin=128, Cout=256, VALID) + bias + BN(inference)
// via XNOR-popcount on bit-packed signs.
//
// out(b,t,co) = p*A[co] + C[co], p = popc over 384 xor'd bits,
// A = -2/sqrt(var+eps), C = (384+bias-mean)/sqrt(var+eps) + beta.
//
// R8: split into UNIDIRECTIONAL streams (mixed read/write HBM turnaround
//     theory; fill kernel proves pure-write hits 7 TB/s):
//  - pack_x: read 67 MB x, write 2 MB packed bits (one uint4/row). Ballot
//    packing (masks are wave-uniform, 2 lanes store per pair).
//  - conv:   read 2 MB bits via wave-uniform broadcast loads (L2-resident),
//    write 131 MB NT stores. No clamping needed (max row t0+33 <= 2047).
// Bit order: word i bit b <-> cin = 4b+i (float4-lane ballot order); kbT
// uses the same permutation, popcount is permutation-invariant.

#define B 64
#define T 2048
#define CIN 128
#define COUT 256
#define KW 3
#define TOUT (T - KW + 1)   // 2046
#define TW 32               // outputs per wave-window (conv)
#define NWIN 64             // windows per row; last overlaps (t0=2014)
#define WPB 4               // waves per block
#define PACK_ROWS 32        // rows packed per wave (16 float4 loads)

typedef float f32x4 __attribute__((ext_vector_type(4)));

// ---- pack kernel signs, transposed co-major layout ----
// kbT[co*12 + k*4 + i], word i bit b <-> cin = 4b+i
__global__ __launch_bounds__(256) void pack_w_kernel(const float* __restrict__ ker,
                                                     const float* __restrict__ bias,
                                                     const float* __restrict__ beta,
                                                     const float* __restrict__ mean,
                                                     const float* __restrict__ var,
                                                     uint32_t* __restrict__ kbT,
                                                     float* __restrict__ A,
                                                     float* __restrict__ C) {
    int k  = blockIdx.x >> 2;       // 0..2
    int i  = blockIdx.x & 3;        // word index 0..3
    int co = threadIdx.x;           // 0..255
    const float* src = ker + ((size_t)(k * CIN + i)) * COUT + co;
    uint32_t wbits = 0;
    #pragma unroll 8
    for (int bb = 0; bb < 32; ++bb) {
        if (src[(size_t)(4 * bb) * COUT] >= 0.0f) wbits |= (1u << bb);
    }
    kbT[(size_t)co * 12 + k * 4 + i] = wbits;
    if (blockIdx.x == 0) {
        float inv = 1.0f / sqrtf(var[co] + 1e-3f);
        A[co] = -2.0f * inv;
        C[co] = (384.0f + bias[co] - mean[co]) * inv + beta[co];
    }
}

// ---- pass 1: pack x signs -> xb[row] = uint4 (128 bits, permuted order) ----
__global__ __launch_bounds__(256) void pack_x_kernel(const float* __restrict__ x,
                                                     uint4* __restrict__ xb) {
    const int l   = threadIdx.x & 63;
    const int wid = blockIdx.x * WPB + (threadIdx.x >> 6);   // 0..4095
    const size_t row0 = (size_t)wid * PACK_ROWS;
    const float* p = x + row0 * CIN + l * 4;
    uint4* q = xb + row0;

    #pragma unroll 4
    for (int i = 0; i < PACK_ROWS / 2; ++i) {
        float4 v = *(const float4*)(p + (size_t)i * 2 * CIN);
        uint64_t m0 = __ballot(v.x >= 0.0f);
        uint64_t m1 = __ballot(v.y >= 0.0f);
        uint64_t m2 = __ballot(v.z >= 0.0f);
        uint64_t m3 = __ballot(v.w >= 0.0f);
        if (l == 0) {
            q[2 * i] = make_uint4((uint32_t)m0, (uint32_t)m1,
                                  (uint32_t)m2, (uint32_t)m3);
        } else if (l == 1) {
            q[2 * i + 1] = make_uint4((uint32_t)(m0 >> 32), (uint32_t)(m1 >> 32),
                                      (uint32_t)(m2 >> 32), (uint32_t)(m3 >> 32));
        }
    }
}

__device__ __forceinline__ int popc4(uint4 r, uint4 k) {
    return __popc(r.x ^ k.x) + __popc(r.y ^ k.y) + __popc(r.z ^ k.z) + __popc(r.w ^ k.w);
}

// ---- pass 2: conv from packed bits (pure-write stream) ----
__global__ __launch_bounds__(256) void conv_kernel(const uint4* __restrict__ xb,
                                                   const uint32_t* __restrict__ kbT,
                                                   const float* __restrict__ A,
                                                   const float* __restrict__ C,
                                                   float* __restrict__ out) {
    const int l   = threadIdx.x & 63;
    const int wv  = threadIdx.x >> 6;
    const int gw  = blockIdx.x * WPB + wv;          // 0..B*NWIN-1
    const int b   = gw >> 6;                        // /NWIN
    const int win = gw & (NWIN - 1);
    const int t0  = (win < NWIN - 1) ? win * TW : (TOUT - TW);  // last overlaps

    // per-thread kernel bits: kj[j][k] = 4 words for cout co0+j, tap k
    const int co0 = l * 4;
    uint4 kj[4][KW];
    #pragma unroll
    for (int j = 0; j < 4; ++j)
        #pragma unroll
        for (int k = 0; k < KW; ++k)
            kj[j][k] = *(const uint4*)(kbT + (size_t)(co0 + j) * 12 + k * 4);
    const float4 av = *(const float4*)(A + co0);
    const float4 cv = *(const float4*)(C + co0);

    // wave-uniform broadcast loads of packed rows (L2/L3-resident, 2 MB total)
    const uint4* xr = xb + (size_t)b * T + t0;
    float* orow = out + ((size_t)b * TOUT + t0) * COUT + co0;

    uint4 r0 = xr[0];
    uint4 r1 = xr[1];
    #pragma unroll 2
    for (int j = 0; j < TW / 4; ++j) {   // 8 bodies, 4 outputs each
        // rows 4j+2 .. 4j+5 (max t0+33 <= 2047: always in-bounds)
        uint4 r2 = xr[4 * j + 2];
        uint4 r3 = xr[4 * j + 3];
        uint4 r4 = xr[4 * j + 4];
        uint4 r5 = xr[4 * j + 5];

        f32x4 o0, o1, o2, o3;
        #pragma unroll
        for (int jj = 0; jj < 4; ++jj) {
            int s0 = popc4(r0, kj[jj][0]) + popc4(r1, kj[jj][1]) + popc4(r2, kj[jj][2]);
            int s1 = popc4(r1, kj[jj][0]) + popc4(r2, kj[jj][1]) + popc4(r3, kj[jj][2]);
            int s2 = popc4(r2, kj[jj][0]) + popc4(r3, kj[jj][1]) + popc4(r4, kj[jj][2]);
            int s3 = popc4(r3, kj[jj][0]) + popc4(r4, kj[jj][1]) + popc4(r5, kj[jj][2]);
            float aj = (&av.x)[jj], cj = (&cv.x)[jj];
            o0[jj] = fmaf((float)s0, aj, cj);
            o1[jj] = fmaf((float)s1, aj, cj);
            o2[jj] = fmaf((float)s2, aj, cj);
            o3[jj] = fmaf((float)s3, aj, cj);
        }

        float* op = orow + (size_t)(4 * j) * COUT;
        __builtin_nontemporal_store(o0, (f32x4*)op);
        __builtin_nontemporal_store(o1, (f32x4*)(op + COUT));
        __builtin_nontemporal_store(o2, (f32x4*)(op + 2 * COUT));
        __builtin_nontemporal_store(o3, (f32x4*)(op + 3 * COUT));

        r0 = r4;
        r1 = r5;
    }
}

extern "C" void kernel_launch(void* const* d_in, const int* in_sizes, int n_in,
                              void* d_out, int out_size, void* d_ws, size_t ws_size,
                              hipStream_t stream) {
    const float* x    = (const float*)d_in[0];
    const float* ker  = (const float*)d_in[1];
    const float* bias = (const float*)d_in[2];
    const float* beta = (const float*)d_in[3];
    const float* mean = (const float*)d_in[4];
    const float* var  = (const float*)d_in[5];
    float* out = (float*)d_out;

    // workspace: kbT (12 KB) | A (1 KB) | C (1 KB) | xbits (2 MB)
    uint32_t* kbT = (uint32_t*)d_ws;
    float*    A   = (float*)(kbT + (size_t)COUT * 12);
    float*    C   = A + COUT;
    uint4*    xb  = (uint4*)(C + COUT);

    pack_x_kernel<<<(B * T / PACK_ROWS) / WPB, 256, 0, stream>>>(x, xb);
    pack_w_kernel<<<KW * 4, 256, 0, stream>>>(ker, bias, beta, mean, var, kbT, A, C);
    conv_kernel<<<(B * NWIN) / WPB, 256, 0, stream>>>(xb, kbT, A, C, out);
}